// Round 1
// baseline (244.700 us; speedup 1.0000x reference)
//
#include <hip/hip_runtime.h>
#include <hip/hip_bf16.h>
#include <stdint.h>

// causal_attention: B=8, C=128, N=H*W=4096, strict causal (j < i), fp32 I/O,
// channel-major [B][C][N] for inputs and output.
//
// Kernel 1 (prep): Qt,Kt = [B][N][C] bf16 transposes; Vb = [B][C][N] bf16
//                  downconvert. All into d_ws (needs 24 MB).
// Kernel 2 (attn): flash attention, 16x16x32 bf16 MFMA, online softmax in
//                  raw-dot domain (exp2((S-m)*log2e/sqrt(128))).

#define BATCH 8
#define CH    128
#define NN    4096
#define QBLK  64
#define KVBLK 64
// log2(e)/sqrt(128)
#define C2 0.12751745f

typedef __attribute__((ext_vector_type(8))) short short8;
typedef __attribute__((ext_vector_type(4))) float f32x4;

__device__ __forceinline__ unsigned short f2bf(float f) {
  union { float f; unsigned u; } x; x.f = f;
  return (unsigned short)((x.u + 0x7fffu + ((x.u >> 16) & 1u)) >> 16);
}

// ---------------- prep: transpose Q,K to [B][N][C] bf16; V to bf16 ----------
__global__ __launch_bounds__(256) void prep_kernel(
    const float* __restrict__ key, const float* __restrict__ mixin,
    const float* __restrict__ query,
    unsigned short* __restrict__ qt, unsigned short* __restrict__ kt,
    unsigned short* __restrict__ vb) {
  int bid = blockIdx.x;
  int t = threadIdx.x;
  if (bid < 8192) {
    __shared__ float tl[32][33];
    const float* src = (bid < 4096) ? query : key;
    unsigned short* dst = (bid < 4096) ? qt : kt;
    int id = bid & 4095;
    int b = id >> 9;          // 512 tiles per batch
    int tile = id & 511;
    int n0 = (tile >> 2) << 5;  // 128 n-tiles of 32
    int c0 = (tile & 3) << 5;   // 4 c-tiles of 32
    const float* sb = src + (size_t)b * CH * NN;
#pragma unroll
    for (int it = 0; it < 4; ++it) {
      int cl = it * 8 + (t >> 5);
      int nl = t & 31;
      tl[cl][nl] = sb[(size_t)(c0 + cl) * NN + n0 + nl];
    }
    __syncthreads();
    int nl = t >> 3;          // 0..31
    int cq = (t & 7) * 4;     // 0..28
    ushort4 o;
    o.x = f2bf(tl[cq + 0][nl]);
    o.y = f2bf(tl[cq + 1][nl]);
    o.z = f2bf(tl[cq + 2][nl]);
    o.w = f2bf(tl[cq + 3][nl]);
    *(ushort4*)&dst[(size_t)(b * NN + n0 + nl) * CH + c0 + cq] = o;
  } else {
    // V downconvert: 1024 blocks x 4096 elems
    int id = bid - 8192;
    size_t base = (size_t)id * 4096 + t * 4;
#pragma unroll
    for (int it = 0; it < 4; ++it) {
      size_t idx = base + (size_t)it * 1024;
      float4 v = *(const float4*)&mixin[idx];
      ushort4 o;
      o.x = f2bf(v.x); o.y = f2bf(v.y); o.z = f2bf(v.z); o.w = f2bf(v.w);
      *(ushort4*)&vb[idx] = o;
    }
  }
}

// ---------------- attention ------------------------------------------------
// LDS: q_lds [64][256B] swz | k_lds [64][256B] swz | v_lds [128][128B] swz |
//      p_lds 4 waves x [16][128B] swz   (total 57344 B)
__global__ __launch_bounds__(256, 2) void attn_kernel(
    const unsigned short* __restrict__ qt, const unsigned short* __restrict__ kt,
    const unsigned short* __restrict__ vb, float* __restrict__ out) {
  __shared__ __align__(16) unsigned char smem[57344];
  unsigned char* q_lds = smem;
  unsigned char* k_lds = smem + 16384;
  unsigned char* v_lds = smem + 32768;
  int tid = threadIdx.x;
  int wid = tid >> 6;
  int lane = tid & 63;
  unsigned char* p_lds = smem + 49152 + wid * 2048;

  int gid = blockIdx.x;
  int b = gid & 7;                 // batch -> XCD (gid%8) for K/V L2 locality
  int i = gid >> 3;                // 0..63
  int qb = (i < 32) ? (63 - i) : (i - 32);  // heavy+light pairing per CU
  int q0 = qb * QBLK;

  const unsigned short* Qb = qt + (size_t)b * NN * CH;
  const unsigned short* Kb = kt + (size_t)b * NN * CH;
  const unsigned short* Vp = vb + (size_t)b * CH * NN;

  // stage Q tile (64 rows x 128 ch), XOR-swizzled
#pragma unroll
  for (int it = 0; it < 4; ++it) {
    int row = it * 16 + (tid >> 4);
    int slot = tid & 15;
    short8 v = *(const short8*)&Qb[(size_t)(q0 + row) * CH + slot * 8];
    *(short8*)&q_lds[row * 256 + ((slot * 16) ^ ((row & 7) << 4))] = v;
  }
  __syncthreads();

  int lr = lane & 15, lg = lane >> 4;
  // hoist Q fragments (reused every KV tile)
  short8 qf[4];
  {
    int row = wid * 16 + lr;
    int swz = (row & 7) << 4;
#pragma unroll
    for (int s = 0; s < 4; ++s)
      qf[s] = *(const short8*)&q_lds[row * 256 + ((s * 64 + lg * 16) ^ swz)];
  }

  f32x4 O[8];
#pragma unroll
  for (int ii = 0; ii < 8; ++ii) O[ii] = (f32x4){0.f, 0.f, 0.f, 0.f};
  float m_r[4], l_r[4];
#pragma unroll
  for (int r = 0; r < 4; ++r) { m_r[r] = -1e30f; l_r[r] = 0.f; }

  int ntiles = qb + 1;   // KV tiles: k in [0, q0+64) ; only last is masked
  for (int kti = 0; kti < ntiles; ++kti) {
    int k0 = kti * KVBLK;
    __syncthreads();   // previous tile fully consumed
    // stage K (64 rows x 128 ch bf16)
#pragma unroll
    for (int it = 0; it < 4; ++it) {
      int row = it * 16 + (tid >> 4);
      int slot = tid & 15;
      short8 v = *(const short8*)&Kb[(size_t)(k0 + row) * CH + slot * 8];
      *(short8*)&k_lds[row * 256 + ((slot * 16) ^ ((row & 7) << 4))] = v;
    }
    // stage V (128 ch x 64 k bf16), native [c][k] layout
#pragma unroll
    for (int it = 0; it < 4; ++it) {
      int c = it * 32 + (tid >> 3);
      int slot = tid & 7;
      short8 v = *(const short8*)&Vp[(size_t)c * NN + k0 + slot * 8];
      *(short8*)&v_lds[c * 128 + ((slot * 16) ^ ((c & 7) << 4))] = v;
    }
    __syncthreads();

    // S = Q K^T  (per wave: 16 q x 64 k)
    f32x4 S[4];
#pragma unroll
    for (int nt = 0; nt < 4; ++nt) S[nt] = (f32x4){0.f, 0.f, 0.f, 0.f};
#pragma unroll
    for (int nt = 0; nt < 4; ++nt) {
      int row = nt * 16 + lr;
      int swz = (row & 7) << 4;
#pragma unroll
      for (int s = 0; s < 4; ++s) {
        short8 kf = *(const short8*)&k_lds[row * 256 + ((s * 64 + lg * 16) ^ swz)];
        S[nt] = __builtin_amdgcn_mfma_f32_16x16x32_bf16(qf[s], kf, S[nt], 0, 0, 0);
      }
    }

    if (kti == qb) {   // diagonal tile: mask k >= q (strict causal)
#pragma unroll
      for (int nt = 0; nt < 4; ++nt) {
        int kl = nt * 16 + lr;
#pragma unroll
        for (int r = 0; r < 4; ++r) {
          int ql = wid * 16 + lg * 4 + r;
          if (kl >= ql) S[nt][r] = -__builtin_inff();
        }
      }
    }

    // online softmax (raw-dot domain), rows spread over 16 lanes x 4 nt
    float alpha[4];
#pragma unroll
    for (int r = 0; r < 4; ++r) {
      float mx = fmaxf(fmaxf(S[0][r], S[1][r]), fmaxf(S[2][r], S[3][r]));
      mx = fmaxf(mx, __shfl_xor(mx, 1));
      mx = fmaxf(mx, __shfl_xor(mx, 2));
      mx = fmaxf(mx, __shfl_xor(mx, 4));
      mx = fmaxf(mx, __shfl_xor(mx, 8));
      float mn = fmaxf(m_r[r], mx);
      alpha[r] = exp2f((m_r[r] - mn) * C2);
      m_r[r] = mn;
      float rs = 0.f;
#pragma unroll
      for (int nt = 0; nt < 4; ++nt) {
        float pv = exp2f((S[nt][r] - mn) * C2);  // -inf -> 0
        S[nt][r] = pv;
        rs += pv;
      }
      rs += __shfl_xor(rs, 1);
      rs += __shfl_xor(rs, 2);
      rs += __shfl_xor(rs, 4);
      rs += __shfl_xor(rs, 8);
      l_r[r] = l_r[r] * alpha[r] + rs;
    }
#pragma unroll
    for (int ct = 0; ct < 8; ++ct)
#pragma unroll
      for (int r = 0; r < 4; ++r) O[ct][r] *= alpha[r];

    // P -> bf16 -> per-wave p_lds [16][64] swz
#pragma unroll
    for (int nt = 0; nt < 4; ++nt)
#pragma unroll
      for (int r = 0; r < 4; ++r) {
        int prow = lg * 4 + r;
        *(unsigned short*)&p_lds[prow * 128 +
                                 ((nt * 32 + lr * 2) ^ ((prow & 7) << 4))] =
            f2bf(S[nt][r]);
      }

    // O += P V
#pragma unroll
    for (int kk = 0; kk < 2; ++kk) {
      short8 pf = *(const short8*)&p_lds[lr * 128 +
                                         ((kk * 64 + lg * 16) ^ ((lr & 7) << 4))];
#pragma unroll
      for (int ct = 0; ct < 8; ++ct) {
        int c = ct * 16 + lr;
        short8 vf = *(const short8*)&v_lds[c * 128 +
                                           ((kk * 64 + lg * 16) ^ ((c & 7) << 4))];
        O[ct] = __builtin_amdgcn_mfma_f32_16x16x32_bf16(pf, vf, O[ct], 0, 0, 0);
      }
    }
  }

  // epilogue: out[b][c][q] = O / (l + 1e-6), fp32, dwordx4 along q
  float rd[4];
#pragma unroll
  for (int r = 0; r < 4; ++r) rd[r] = 1.f / (l_r[r] + 1e-6f);
  int qbase = q0 + wid * 16 + lg * 4;
#pragma unroll
  for (int ct = 0; ct < 8; ++ct) {
    int c = ct * 16 + lr;
    f32x4 o;
#pragma unroll
    for (int r = 0; r < 4; ++r) o[r] = O[ct][r] * rd[r];
    *(f32x4*)&out[(size_t)(b * CH + c) * NN + qbase] = o;
  }
}

extern "C" void kernel_launch(void* const* d_in, const int* in_sizes, int n_in,
                              void* d_out, int out_size, void* d_ws, size_t ws_size,
                              hipStream_t stream) {
  const float* key = (const float*)d_in[0];
  const float* mixin = (const float*)d_in[1];
  const float* query = (const float*)d_in[2];
  float* out = (float*)d_out;

  // ws: Qt (8 MB) | Kt (8 MB) | Vb (8 MB)  -- needs 24 MB
  unsigned short* qt = (unsigned short*)d_ws;
  unsigned short* kt = qt + (size_t)BATCH * NN * CH;
  unsigned short* vb = kt + (size_t)BATCH * NN * CH;

  prep_kernel<<<9216, 256, 0, stream>>>(key, mixin, query, qt, kt, vb);
  attn_kernel<<<512, 256, 0, stream>>>(qt, kt, vb, out);
}

// Round 4
// 188.866 us; speedup vs baseline: 1.2956x; 1.2956x over previous
//
#include <hip/hip_runtime.h>
#include <hip/hip_bf16.h>
#include <stdint.h>

// causal_attention: B=8, C=128, N=4096, strict causal (j<i), fp32 I/O, [B][C][N].
// prep: Qt,Kt=[B][N][C] bf16 (transpose, cvt_pk), Vb=[B][C][N] bf16. ws: 24MB.
// attn: flash attention, 32x32x16 bf16 MFMA, swapped operands BOTH sides:
//       S^T = K*Q^T (D col = q = lane&31 -> lane-local softmax) and
//       O^T = V^T*P^T (D col = q = lane&31 -> lane-local rescale/divide).
//       P repack via v_cvt_pk_bf16_f32 + __builtin_amdgcn_permlane32_swap;
//       cross-half m/l combine via __shfl_xor(x,32) (reg-coalescing-safe);
//       4 waves = 2 q-halves x 2 kv-tile-parity groups (merged at end);
//       global_load_lds staging with pre-swizzled source, 1 barrier/tile.

#define BATCH 8
#define CH    128
#define NN    4096
#define QBLK  64
#define KVBLK 64
#define C2 0.12751745f   // log2(e)/sqrt(128)

typedef __attribute__((ext_vector_type(8))) short short8;
typedef __attribute__((ext_vector_type(16))) float f32x16;
typedef __attribute__((ext_vector_type(2))) int v2i;

__device__ __forceinline__ void gload16(const void* g, void* l) {
  __builtin_amdgcn_global_load_lds(
      (const __attribute__((address_space(1))) void*)g,
      (__attribute__((address_space(3))) void*)l, 16, 0, 0);
}

__device__ __forceinline__ int pk_bf16(float lo, float hi) {
  int d;
  asm("v_cvt_pk_bf16_f32 %0, %1, %2" : "=v"(d) : "v"(lo), "v"(hi));
  return d;
}

// exchange dst-high-32-lanes with src-low-32-lanes (two-register codegen
// guaranteed by the builtin; inline-asm with equal values can coalesce!)
__device__ __forceinline__ void plswap(int& a, int& b) {
  v2i r = __builtin_amdgcn_permlane32_swap(a, b, false, false);
  a = r[0]; b = r[1];
}

// ---------------- prep ------------------------------------------------------
__global__ __launch_bounds__(256) void prep_kernel(
    const float* __restrict__ key, const float* __restrict__ mixin,
    const float* __restrict__ query,
    unsigned short* __restrict__ qt, unsigned short* __restrict__ kt,
    unsigned short* __restrict__ vb) {
  int bid = blockIdx.x;
  int t = threadIdx.x;
  if (bid < 8192) {
    __shared__ float tl[32][33];
    const float* src = (bid < 4096) ? query : key;
    unsigned short* dst = (bid < 4096) ? qt : kt;
    int id = bid & 4095;
    int b = id >> 9;
    int tile = id & 511;
    int n0 = (tile >> 2) << 5;
    int c0 = (tile & 3) << 5;
    const float* sb = src + (size_t)b * CH * NN;
#pragma unroll
    for (int it = 0; it < 4; ++it) {
      int cl = it * 8 + (t >> 5);
      int nl = t & 31;
      tl[cl][nl] = sb[(size_t)(c0 + cl) * NN + n0 + nl];
    }
    __syncthreads();
    int nl = t >> 3;
    int cq = (t & 7) * 4;
    int d0 = pk_bf16(tl[cq + 0][nl], tl[cq + 1][nl]);
    int d1 = pk_bf16(tl[cq + 2][nl], tl[cq + 3][nl]);
    *(v2i*)&dst[(size_t)(b * NN + n0 + nl) * CH + c0 + cq] = (v2i){d0, d1};
  } else {
    int id = bid - 8192;
    size_t base = (size_t)id * 4096 + t * 4;
#pragma unroll
    for (int it = 0; it < 4; ++it) {
      size_t idx = base + (size_t)it * 1024;
      float4 v = *(const float4*)&mixin[idx];
      int d0 = pk_bf16(v.x, v.y);
      int d1 = pk_bf16(v.z, v.w);
      *(v2i*)&vb[idx] = (v2i){d0, d1};
    }
  }
}

// ---------------- attention -------------------------------------------------
// LDS: 2 buffers x (K 16KB + V 16KB) = 64KB. Q staged once in buf1's K region.
// K/V rows XOR-swizzled: LDS linear slot s holds source slot s^(row&7) (16B).
__global__ __launch_bounds__(256, 2) void attn_kernel(
    const unsigned short* __restrict__ qt, const unsigned short* __restrict__ kt,
    const unsigned short* __restrict__ vb, float* __restrict__ out) {
  __shared__ __align__(16) unsigned char smem[65536];
  int tid = threadIdx.x;
  int wid = tid >> 6;
  int lane = tid & 63;
  int l31 = lane & 31;
  int hi = lane >> 5;
  int swz = (lane & 7) << 4;
  int qhalf = wid & 1;     // which 32-q half of the 64-q block
  int h = wid >> 1;        // kv-tile parity group

  int gid = blockIdx.x;
  int b = gid & 7;                          // batch -> XCD
  int i = gid >> 3;
  int qb = (i < 32) ? (63 - i) : (i - 32);  // heavy+light pairing
  int q0 = qb * QBLK;
  int ntiles = qb + 1;

  const unsigned char* Qb = (const unsigned char*)(qt + (size_t)b * NN * CH);
  const unsigned char* Kb = (const unsigned char*)(kt + (size_t)b * NN * CH);
  const unsigned char* Vp = (const unsigned char*)(vb + (size_t)b * CH * NN);

  // per-lane staging source offsets (pre-swizzled so linear LDS dest ends up
  // holding swizzled content; global_load_lds writes base + lane*16)
  int kg[4], vg[4];
#pragma unroll
  for (int i2 = 0; i2 < 4; ++i2) {
    int row = wid * 16 + i2 * 4 + (lane >> 4);
    int slot = (lane & 15) ^ (row & 7);
    kg[i2] = row * 256 + slot * 16;            // bytes within K tile
    int c = wid * 32 + i2 * 8 + (lane >> 3);
    int vslot = (lane & 7) ^ (c & 7);
    vg[i2] = c * 8192 + vslot * 16;            // bytes; c*NN*2 + k-slot*16
  }

  // prologue: stage Q (buf1 K region) + tile 0 (buf0)
#pragma unroll
  for (int i2 = 0; i2 < 4; ++i2) {
    gload16(Qb + (size_t)q0 * 256 + kg[i2], smem + 32768 + wid * 4096 + i2 * 1024);
    gload16(Kb + kg[i2], smem + wid * 4096 + i2 * 1024);
    gload16(Vp + vg[i2], smem + 16384 + wid * 4096 + i2 * 1024);
  }
  __syncthreads();

  // hoist Q fragments (B operand: col=q=l31, 8 contiguous c per lane)
  short8 qf[8];
  {
    int qrb = 32768 + (qhalf * 32 + l31) * 256;
#pragma unroll
    for (int cs = 0; cs < 8; ++cs)
      qf[cs] = *(const short8*)&smem[qrb + ((cs * 32 + hi * 16) ^ swz)];
  }
  __syncthreads();

  f32x16 O[4];
#pragma unroll
  for (int ct = 0; ct < 4; ++ct)
#pragma unroll
    for (int r = 0; r < 16; ++r) O[ct][r] = 0.f;
  float m_run = -1e30f, l_run = 0.f;

  for (int t = 0; t < ntiles; ++t) {
    if (t + 1 < ntiles) {  // stage next tile (overlaps with compute below)
      unsigned char* bk = smem + ((t + 1) & 1) * 32768;
      const unsigned char* Ks = Kb + (size_t)(t + 1) * 16384;
      const unsigned char* Vs = Vp + (size_t)(t + 1) * 128;
#pragma unroll
      for (int i2 = 0; i2 < 4; ++i2) {
        gload16(Ks + kg[i2], bk + wid * 4096 + i2 * 1024);
        gload16(Vs + vg[i2], bk + 16384 + wid * 4096 + i2 * 1024);
      }
    }
    if ((t & 1) == h) {
      const unsigned char* bk = smem + (t & 1) * 32768;
      const unsigned char* bv = bk + 16384;
      // S^T = K * Q^T : D[k][q], col=lane&31=q, row k=crow(r,hi)
      f32x16 S0, S1;
#pragma unroll
      for (int r = 0; r < 16; ++r) { S0[r] = 0.f; S1[r] = 0.f; }
#pragma unroll
      for (int cs = 0; cs < 8; ++cs) {
        int wo = (cs * 32 + hi * 16) ^ swz;
        short8 k0f = *(const short8*)&bk[l31 * 256 + wo];
        short8 k1f = *(const short8*)&bk[8192 + l31 * 256 + wo];
        S0 = __builtin_amdgcn_mfma_f32_32x32x16_bf16(k0f, qf[cs], S0, 0, 0, 0);
        S1 = __builtin_amdgcn_mfma_f32_32x32x16_bf16(k1f, qf[cs], S1, 0, 0, 0);
      }
      if (t == qb) {  // diagonal: mask k >= q (strict causal)
        int ql = qhalf * 32 + l31;
#pragma unroll
        for (int r = 0; r < 16; ++r) {
          int kl = (r & 3) + 8 * (r >> 2) + 4 * hi;
          if (kl >= ql)      S0[r] = -__builtin_inff();
          if (kl + 32 >= ql) S1[r] = -__builtin_inff();
        }
      }
      // online softmax — lane-local over 32 k, + cross-half combine (lane^32)
      float mx = S0[0];
#pragma unroll
      for (int r = 1; r < 16; ++r) mx = fmaxf(mx, S0[r]);
#pragma unroll
      for (int r = 0; r < 16; ++r) mx = fmaxf(mx, S1[r]);
      mx = fmaxf(mx, __shfl_xor(mx, 32));
      float mn = fmaxf(m_run, mx);
      float al = __builtin_amdgcn_exp2f((m_run - mn) * C2);
      m_run = mn;
      float rs = 0.f;
#pragma unroll
      for (int r = 0; r < 16; ++r) {
        S0[r] = __builtin_amdgcn_exp2f((S0[r] - mn) * C2);
        rs += S0[r];
      }
#pragma unroll
      for (int r = 0; r < 16; ++r) {
        S1[r] = __builtin_amdgcn_exp2f((S1[r] - mn) * C2);
        rs += S1[r];
      }
      rs += __shfl_xor(rs, 32);
      l_run = l_run * al + rs;
#pragma unroll
      for (int ct = 0; ct < 4; ++ct)
#pragma unroll
        for (int r = 0; r < 16; ++r) O[ct][r] *= al;
      // P repack (cvt_pk + permlane32_swap): lane(q=l31,hi) gets
      // k = ks*16 + 8*hi + j  -> B-operand of O^T = V^T * P^T
#pragma unroll
      for (int ks = 0; ks < 4; ++ks) {
        const f32x16& Sv = (ks >= 2) ? S1 : S0;
        int b8 = (ks & 1) * 8;
        int cA = pk_bf16(Sv[b8 + 0], Sv[b8 + 1]);
        int cB = pk_bf16(Sv[b8 + 2], Sv[b8 + 3]);
        int cC = pk_bf16(Sv[b8 + 4], Sv[b8 + 5]);
        int cD = pk_bf16(Sv[b8 + 6], Sv[b8 + 7]);
        plswap(cA, cC);
        plswap(cB, cD);
        union { int w[4]; short8 s; } pu;
        pu.w[0] = cA; pu.w[1] = cB; pu.w[2] = cC; pu.w[3] = cD;
        int vwo = (ks * 32 + hi * 16) ^ swz;
        // O^T = V^T * P^T: A = V^T (row=c=lane&31), B = P^T (col=q=lane&31)
        // -> D col = q = lane&31, D row = c-sub = crow(r,hi)
#pragma unroll
        for (int ct = 0; ct < 4; ++ct) {
          short8 vf = *(const short8*)&bv[(ct * 32 + l31) * 128 + vwo];
          O[ct] = __builtin_amdgcn_mfma_f32_32x32x16_bf16(vf, pu.s, O[ct], 0, 0, 0);
        }
      }
    }
    __syncthreads();
  }

  // merge the two kv-parity partials (flash combine), then store.
  // O[ct][r] holds (c = ct*32 + crow(r,hi), q = qhalf*32 + l31); m/l per-lane.
  float* mlb = (float*)smem;                  // 2KB
  float* ob = (float*)(smem + 4096);          // 32KB (h=1 waves' O)
  mlb[(wid * 64 + lane) * 2 + 0] = m_run;
  mlb[(wid * 64 + lane) * 2 + 1] = l_run;
  if (h == 1) {
#pragma unroll
    for (int ct = 0; ct < 4; ++ct)
#pragma unroll
      for (int r = 0; r < 16; ++r) {
        int c = ct * 32 + (r & 3) + 8 * (r >> 2) + 4 * hi;
        ob[c * 64 + qhalf * 32 + l31] = O[ct][r];
      }
  }
  __syncthreads();
  if (h == 0) {
    int pw = wid + 2;
    float m1 = mlb[(pw * 64 + lane) * 2 + 0];
    float l1 = mlb[(pw * 64 + lane) * 2 + 1];
    float ms = fmaxf(m_run, m1);
    float a0 = __builtin_amdgcn_exp2f((m_run - ms) * C2);
    float a1 = __builtin_amdgcn_exp2f((m1 - ms) * C2);
    float lt = l_run * a0 + l1 * a1;
    float rd = 1.0f / (lt + 1e-6f);
    int q = q0 + qhalf * 32 + l31;
#pragma unroll
    for (int ct = 0; ct < 4; ++ct)
#pragma unroll
      for (int r = 0; r < 16; ++r) {
        int c = ct * 32 + (r & 3) + 8 * (r >> 2) + 4 * hi;
        float v = (O[ct][r] * a0 + ob[c * 64 + qhalf * 32 + l31] * a1) * rd;
        out[(size_t)(b * CH + c) * NN + q] = v;
      }
  }
}

extern "C" void kernel_launch(void* const* d_in, const int* in_sizes, int n_in,
                              void* d_out, int out_size, void* d_ws, size_t ws_size,
                              hipStream_t stream) {
  const float* key = (const float*)d_in[0];
  const float* mixin = (const float*)d_in[1];
  const float* query = (const float*)d_in[2];
  float* out = (float*)d_out;

  unsigned short* qtp = (unsigned short*)d_ws;
  unsigned short* ktp = qtp + (size_t)BATCH * NN * CH;
  unsigned short* vbp = ktp + (size_t)BATCH * NN * CH;

  prep_kernel<<<9216, 256, 0, stream>>>(key, mixin, query, qtp, ktp, vbp);
  attn_kernel<<<512, 256, 0, stream>>>(qtp, ktp, vbp, out);
}